// Round 14
// baseline (253.764 us; speedup 1.0000x reference)
//
#include <hip/hip_runtime.h>
#include <stdint.h>

// DiffLogic: 3-layer differentiable logic network.
// Round 20: attack the REAL critical path found via R13's FETCH_SIZE: the
// 9.2MB meta stream is HBM-sourced (read once), so every iteration's 9
// s_loads pay ~900cy + an lgkmcnt(0) FULL DRAIN (SMEM is out-of-order)
// before the gathers can even start. Per-iter chain ~1350cy x16 = ~9us/wave
// with poor cross-wave overlap -> fused ~33us @ VALUBusy 20%.
// Fix: SGPR double-buffer at pair granularity -- load pair B's metadata
// (72 SGPRs) while evaluating pair A, alternating (4 unrolled trips).
// Prefetch distance = 2 gate-evals ~ 900cy = HBM latency covered.
// All names static (macros, no arrays); everything else = R13 artifact.

#define BATCH   256
#define IN_DIM  1024
#define WIDTH   64000
#define NGROUP  10
#define GSIZE   6400      // WIDTH / NGROUP
#define TAU     30.0f
#define NWAVE   16        // waves per block (1024 threads)
#define GPB3    256       // gates per block; 6400 % 256 == 0 -> no straddle
#define GPW3    (GPB3/NWAVE)   // 16 gates per wave
#define NBLK3   (WIDTH/GPB3)   // 250 blocks -> 1 block/CU, single pass
#define BPG     (GSIZE/GPB3)   // 25 blocks per output group

typedef unsigned short ushort_t;

static __device__ __forceinline__ ushort_t f2bf(float f) {   // RNE
    uint32_t u = __float_as_uint(f);
    return (ushort_t)((u + 0x7fffu + ((u >> 16) & 1u)) >> 16);
}
static __device__ __forceinline__ float bfl(uint32_t u) {    // low bf16 -> f32
    return __uint_as_float(u << 16);
}
static __device__ __forceinline__ float bfh(uint32_t u) {    // high bf16 -> f32
    return __uint_as_float(u & 0xffff0000u);
}
// h = c0 + c1*a + c2*b + c3*(a*b) = b*(c3*a+c2) + (c1*a+c0)  -- 3 FMA
static __device__ __forceinline__ float gate1(float4 c, float a, float b) {
    return fmaf(b, fmaf(c.w, a, c.z), fmaf(c.y, a, c.x));
}
static __device__ __forceinline__ float4 gate4(float4 c, float4 a, float4 b) {
    float4 r;
    r.x = gate1(c, a.x, b.x);
    r.y = gate1(c, a.y, b.y);
    r.z = gate1(c, a.z, b.z);
    r.w = gate1(c, a.w, b.w);
    return r;
}
// packed inputs: a,b are uint2 holding 4 bf16 batch elems each
static __device__ __forceinline__ float4 gate4u(float4 c, uint2 a, uint2 b) {
    float4 r;
    r.x = gate1(c, bfl(a.x), bfl(b.x));
    r.y = gate1(c, bfh(a.x), bfh(b.x));
    r.z = gate1(c, bfl(a.y), bfl(b.y));
    r.w = gate1(c, bfh(a.y), bfh(b.y));
    return r;
}

// ---------------------------------------------------------------- transpose
// x:(256,1024) f32 row-major -> xT:(1024,256) bf16
__global__ __launch_bounds__(256) void transpose_kernel(
    const float* __restrict__ x, ushort_t* __restrict__ xT)
{
    __shared__ float tile[64][65];
    const int c0 = (blockIdx.x & 15) * 64;
    const int b0 = (blockIdx.x >> 4) * 64;
    const int lt = threadIdx.x & 63;
    const int wt = threadIdx.x >> 6;
    for (int r = wt; r < 64; r += 4)
        tile[r][lt] = x[(b0 + r) * IN_DIM + c0 + lt];
    __syncthreads();
    for (int r = wt; r < 64; r += 4)
        xT[(c0 + r) * BATCH + b0 + lt] = f2bf(tile[lt][r]);
}

// ---------------------------------------------------------------- coefficients
__global__ __launch_bounds__(256) void coef_kernel(
    const float* __restrict__ w1, const float* __restrict__ w2,
    const float* __restrict__ w3,
    float4* __restrict__ c1o, float4* __restrict__ c2o, float4* __restrict__ c3o)
{
    const int id = blockIdx.x * 256 + threadIdx.x;
    const int layer = id / WIDTH;
    const int j = id - layer * WIDTH;
    const float* w = (layer == 0) ? w1 : (layer == 1) ? w2 : w3;
    float4* cc     = (layer == 0) ? c1o : (layer == 1) ? c2o : c3o;

    const float4* w4 = (const float4*)(w + (size_t)j * 16);
    float4 q0 = w4[0], q1 = w4[1], q2 = w4[2], q3 = w4[3];
    float p[16] = {q0.x,q0.y,q0.z,q0.w, q1.x,q1.y,q1.z,q1.w,
                   q2.x,q2.y,q2.z,q2.w, q3.x,q3.y,q3.z,q3.w};
    float m = p[0];
    #pragma unroll
    for (int i = 1; i < 16; ++i) m = fmaxf(m, p[i]);
    float s = 0.f;
    #pragma unroll
    for (int i = 0; i < 16; ++i) { p[i] = __expf(p[i] - m); s += p[i]; }
    const float inv = 1.0f / s;
    float c0 = (p[8]+p[9]+p[10]+p[11]+p[12]+p[13]+p[14]+p[15]) * inv;
    float c1 = (p[2]+p[3]+p[6]+p[7] - p[8]-p[9]-p[12]-p[13]) * inv;
    float c2 = (p[4]+p[5]+p[6]+p[7] - p[8]-p[9]-p[10]-p[11]) * inv;
    float c3 = (p[1]-p[2]-p[4]-2.f*p[6]-p[7]+p[8]+2.f*p[9]+p[11]+p[13]-p[14]) * inv;
    cc[j] = make_float4(c0, c1, c2, c3);
}

// ---------------------------------------------------------------- tree prep
// One thread per final gate j: flatten its depth-3 tree into a single
// 36-dword record: [iA(4) | iB(4) | K0..K6(28)] -> s_loads in the hot loop.
__global__ __launch_bounds__(256) void prep_kernel(
    const int* __restrict__ ia1, const int* __restrict__ ib1,
    const int* __restrict__ ia2, const int* __restrict__ ib2,
    const int* __restrict__ ia3, const int* __restrict__ ib3,
    const float4* __restrict__ c1, const float4* __restrict__ c2,
    const float4* __restrict__ c3,
    int* __restrict__ meta)        // [WIDTH][36]
{
    const int j = blockIdx.x * 256 + threadIdx.x;
    if (j >= WIDTH) return;

    const int pa = ia3[j], pb = ib3[j];
    const int qaa = ia2[pa], qab = ib2[pa];
    const int qba = ia2[pb], qbb = ib2[pb];

    int* M = meta + (size_t)j * 36;
    M[0] = ia1[qaa]; M[1] = ib1[qaa];
    M[2] = ia1[qab]; M[3] = ib1[qab];
    M[4] = ia1[qba]; M[5] = ib1[qba];
    M[6] = ia1[qbb]; M[7] = ib1[qbb];

    float4* P = (float4*)(M + 8);
    P[0] = c1[qaa]; P[1] = c1[qab]; P[2] = c1[qba]; P[3] = c1[qbb];
    P[4] = c2[pa];  P[5] = c2[pb];
    P[6] = c3[j];
}

// ---------------------------------------------------------------- fused net
// SGPR-resident metadata for one gate: 2 int4 + 7 float4 = 36 dwords.
// DECLG/LOADG/EVALG operate on NAMED variable sets (token-pasted), so
// nothing is runtime-indexed and nothing can be address-taken.
#define DECLG(S) \
    int4 S##iA, S##iB; \
    float4 S##K0, S##K1, S##K2, S##K3, S##K4, S##K5, S##K6;

#define LOADG(S, g) do { \
    const int* mp_ = meta + (size_t)(g) * 36; \
    S##iA = *(const int4*)(mp_);      S##iB = *(const int4*)(mp_ + 4); \
    S##K0 = *(const float4*)(mp_ + 8);  S##K1 = *(const float4*)(mp_ + 12); \
    S##K2 = *(const float4*)(mp_ + 16); S##K3 = *(const float4*)(mp_ + 20); \
    S##K4 = *(const float4*)(mp_ + 24); S##K5 = *(const float4*)(mp_ + 28); \
    S##K6 = *(const float4*)(mp_ + 32); \
} while (0)

#define EVALG(S) do { \
    const uint2 q0_ = ((const uint2*)(xT + (size_t)S##iA.x * BATCH))[lane]; \
    const uint2 q1_ = ((const uint2*)(xT + (size_t)S##iA.y * BATCH))[lane]; \
    const uint2 q2_ = ((const uint2*)(xT + (size_t)S##iA.z * BATCH))[lane]; \
    const uint2 q3_ = ((const uint2*)(xT + (size_t)S##iA.w * BATCH))[lane]; \
    const uint2 q4_ = ((const uint2*)(xT + (size_t)S##iB.x * BATCH))[lane]; \
    const uint2 q5_ = ((const uint2*)(xT + (size_t)S##iB.y * BATCH))[lane]; \
    const uint2 q6_ = ((const uint2*)(xT + (size_t)S##iB.z * BATCH))[lane]; \
    const uint2 q7_ = ((const uint2*)(xT + (size_t)S##iB.w * BATCH))[lane]; \
    const float4 haa_ = gate4u(S##K0, q0_, q1_); \
    const float4 hab_ = gate4u(S##K1, q2_, q3_); \
    const float4 hba_ = gate4u(S##K2, q4_, q5_); \
    const float4 hbb_ = gate4u(S##K3, q6_, q7_); \
    const float4 h2a_ = gate4(S##K4, haa_, hab_); \
    const float4 h2b_ = gate4(S##K5, hba_, hbb_); \
    const float4 h3_  = gate4(S##K6, h2a_, h2b_); \
    acc.x += h3_.x; acc.y += h3_.y; acc.z += h3_.z; acc.w += h3_.w; \
} while (0)

__global__ __launch_bounds__(1024, 4) void fused_kernel(
    const ushort_t* __restrict__ xT,
    const int*      __restrict__ meta,
    float*          __restrict__ red_out)
{
    __shared__ float4 sred[NWAVE][64];       // 16 KB

    const int tid  = threadIdx.x;
    const int lane = tid & 63;
    const int wu   = __builtin_amdgcn_readfirstlane(tid >> 6);
    const int g0   = blockIdx.x * GPB3 + wu * GPW3;   // uniform

    float4 acc = make_float4(0.f, 0.f, 0.f, 0.f);

    // pair sets: A = gates (4t, 4t+1), B = gates (4t+2, 4t+3)
    DECLG(A0) DECLG(A1) DECLG(B0) DECLG(B1)

    LOADG(A0, g0 + 0);
    LOADG(A1, g0 + 1);

    #pragma unroll
    for (int t = 0; t < 4; ++t) {
        const int gb = g0 + 4 * t;
        // prefetch pair B (used ~2 gate-evals = ~900cy later)
        LOADG(B0, gb + 2);
        LOADG(B1, gb + 3);
        EVALG(A0);
        EVALG(A1);
        // prefetch next pair A while B evaluates
        if (t < 3) {
            LOADG(A0, gb + 4);
            LOADG(A1, gb + 5);
        }
        EVALG(B0);
        EVALG(B1);
    }

    // ---- block reduction + grouped atomic add (block fully inside a group)
    sred[wu][lane] = acc;
    __syncthreads();
    if (wu == 0) {
        float4 t = sred[0][lane];
        #pragma unroll
        for (int w = 1; w < NWAVE; ++w) {
            float4 q = sred[w][lane];
            t.x += q.x; t.y += q.y; t.z += q.z; t.w += q.w;
        }
        const float sc = 1.0f / TAU;
        const int grp = blockIdx.x / BPG;
        const int b0 = lane * 4;
        atomicAdd(&red_out[(b0 + 0) * NGROUP + grp], t.x * sc);
        atomicAdd(&red_out[(b0 + 1) * NGROUP + grp], t.y * sc);
        atomicAdd(&red_out[(b0 + 2) * NGROUP + grp], t.z * sc);
        atomicAdd(&red_out[(b0 + 3) * NGROUP + grp], t.w * sc);
    }
}

// ---------------------------------------------------------------- launch
extern "C" void kernel_launch(void* const* d_in, const int* in_sizes, int n_in,
                              void* d_out, int out_size, void* d_ws, size_t ws_size,
                              hipStream_t stream)
{
    const float* x   = (const float*)d_in[0];
    const float* w1  = (const float*)d_in[1];
    const float* w2  = (const float*)d_in[2];
    const float* w3  = (const float*)d_in[3];
    const int*   ia1 = (const int*)d_in[4];
    const int*   ib1 = (const int*)d_in[5];
    const int*   ia2 = (const int*)d_in[6];
    const int*   ib2 = (const int*)d_in[7];
    const int*   ia3 = (const int*)d_in[8];
    const int*   ib3 = (const int*)d_in[9];
    float* out = (float*)d_out;

    // workspace: xT (0.5MB) | meta (9.2MB) | c1,c2,c3 (3MB) ~= 12.7MB
    char* ws = (char*)d_ws;
    ushort_t* xT = (ushort_t*)ws;
    int*    meta = (int*)(ws + (size_t)IN_DIM * BATCH * 2);
    float4*   c1 = (float4*)(meta + (size_t)WIDTH * 36);
    float4*   c2 = c1 + WIDTH;
    float4*   c3 = c2 + WIDTH;

    hipMemsetAsync(d_out, 0, (size_t)out_size * sizeof(float), stream);

    transpose_kernel<<<64, 256, 0, stream>>>(x, xT);
    coef_kernel<<<(3 * WIDTH) / 256, 256, 0, stream>>>(w1, w2, w3, c1, c2, c3);
    prep_kernel<<<WIDTH / 256, 256, 0, stream>>>(ia1, ib1, ia2, ib2, ia3, ib3,
                                                 c1, c2, c3, meta);
    fused_kernel<<<NBLK3, 1024, 0, stream>>>(xT, meta, out);
}

// Round 15
// 128.381 us; speedup vs baseline: 1.9766x; 1.9766x over previous
//
#include <hip/hip_runtime.h>
#include <stdint.h>

// DiffLogic: 3-layer differentiable logic network.
// Round 21: R20's SGPR double-buffer spilled (3rd confirmation: named-set
// discipline breaks under conditional reassignment; 144 dwords of meta
// won't stay scalar). Revert it. New combination instead: LDS-staged
// metadata + global gathers -- never tried together. Block's meta slice is
// 36.9KB: stage ONCE (coalesced, 1 barrier), then in-loop meta reads are
// ~120cy broadcast ds_read_b128 instead of ~900cy HBM s_load + lgkmcnt(0)
// full drain (the R19 wall). Keep R15's full-batch gathers (64K evals) and
// (1024,4). LDS staging compiled spill-free in R12/R13 (VGPR 52-88).

#define BATCH   256
#define IN_DIM  1024
#define WIDTH   64000
#define NGROUP  10
#define GSIZE   6400      // WIDTH / NGROUP
#define TAU     30.0f
#define NWAVE   16        // waves per block (1024 threads)
#define GPB3    256       // gates per block; 6400 % 256 == 0 -> no straddle
#define GPW3    (GPB3/NWAVE)   // 16 gates per wave
#define NBLK3   (WIDTH/GPB3)   // 250 blocks -> 1 block/CU, single pass
#define BPG     (GSIZE/GPB3)   // 25 blocks per output group
#define MDW     36             // meta dwords per gate
#define MI4     (GPB3*MDW/4)   // 2304 int4 per block's meta slice

typedef unsigned short ushort_t;

static __device__ __forceinline__ ushort_t f2bf(float f) {   // RNE
    uint32_t u = __float_as_uint(f);
    return (ushort_t)((u + 0x7fffu + ((u >> 16) & 1u)) >> 16);
}
static __device__ __forceinline__ float bfl(uint32_t u) {    // low bf16 -> f32
    return __uint_as_float(u << 16);
}
static __device__ __forceinline__ float bfh(uint32_t u) {    // high bf16 -> f32
    return __uint_as_float(u & 0xffff0000u);
}
// h = c0 + c1*a + c2*b + c3*(a*b) = b*(c3*a+c2) + (c1*a+c0)  -- 3 FMA
static __device__ __forceinline__ float gate1(float4 c, float a, float b) {
    return fmaf(b, fmaf(c.w, a, c.z), fmaf(c.y, a, c.x));
}
static __device__ __forceinline__ float4 gate4(float4 c, float4 a, float4 b) {
    float4 r;
    r.x = gate1(c, a.x, b.x);
    r.y = gate1(c, a.y, b.y);
    r.z = gate1(c, a.z, b.z);
    r.w = gate1(c, a.w, b.w);
    return r;
}
// packed inputs: a,b are uint2 holding 4 bf16 batch elems each
static __device__ __forceinline__ float4 gate4u(float4 c, uint2 a, uint2 b) {
    float4 r;
    r.x = gate1(c, bfl(a.x), bfl(b.x));
    r.y = gate1(c, bfh(a.x), bfh(b.x));
    r.z = gate1(c, bfl(a.y), bfl(b.y));
    r.w = gate1(c, bfh(a.y), bfh(b.y));
    return r;
}

// ---------------------------------------------------------------- transpose
// x:(256,1024) f32 row-major -> xT:(1024,256) bf16
__global__ __launch_bounds__(256) void transpose_kernel(
    const float* __restrict__ x, ushort_t* __restrict__ xT)
{
    __shared__ float tile[64][65];
    const int c0 = (blockIdx.x & 15) * 64;
    const int b0 = (blockIdx.x >> 4) * 64;
    const int lt = threadIdx.x & 63;
    const int wt = threadIdx.x >> 6;
    for (int r = wt; r < 64; r += 4)
        tile[r][lt] = x[(b0 + r) * IN_DIM + c0 + lt];
    __syncthreads();
    for (int r = wt; r < 64; r += 4)
        xT[(c0 + r) * BATCH + b0 + lt] = f2bf(tile[lt][r]);
}

// ---------------------------------------------------------------- coefficients
__global__ __launch_bounds__(256) void coef_kernel(
    const float* __restrict__ w1, const float* __restrict__ w2,
    const float* __restrict__ w3,
    float4* __restrict__ c1o, float4* __restrict__ c2o, float4* __restrict__ c3o)
{
    const int id = blockIdx.x * 256 + threadIdx.x;
    const int layer = id / WIDTH;
    const int j = id - layer * WIDTH;
    const float* w = (layer == 0) ? w1 : (layer == 1) ? w2 : w3;
    float4* cc     = (layer == 0) ? c1o : (layer == 1) ? c2o : c3o;

    const float4* w4 = (const float4*)(w + (size_t)j * 16);
    float4 q0 = w4[0], q1 = w4[1], q2 = w4[2], q3 = w4[3];
    float p[16] = {q0.x,q0.y,q0.z,q0.w, q1.x,q1.y,q1.z,q1.w,
                   q2.x,q2.y,q2.z,q2.w, q3.x,q3.y,q3.z,q3.w};
    float m = p[0];
    #pragma unroll
    for (int i = 1; i < 16; ++i) m = fmaxf(m, p[i]);
    float s = 0.f;
    #pragma unroll
    for (int i = 0; i < 16; ++i) { p[i] = __expf(p[i] - m); s += p[i]; }
    const float inv = 1.0f / s;
    float c0 = (p[8]+p[9]+p[10]+p[11]+p[12]+p[13]+p[14]+p[15]) * inv;
    float c1 = (p[2]+p[3]+p[6]+p[7] - p[8]-p[9]-p[12]-p[13]) * inv;
    float c2 = (p[4]+p[5]+p[6]+p[7] - p[8]-p[9]-p[10]-p[11]) * inv;
    float c3 = (p[1]-p[2]-p[4]-2.f*p[6]-p[7]+p[8]+2.f*p[9]+p[11]+p[13]-p[14]) * inv;
    cc[j] = make_float4(c0, c1, c2, c3);
}

// ---------------------------------------------------------------- tree prep
// One thread per final gate j: flatten its depth-3 tree into a single
// 36-dword record: [iA(4) | iB(4) | K0..K6(28)].
__global__ __launch_bounds__(256) void prep_kernel(
    const int* __restrict__ ia1, const int* __restrict__ ib1,
    const int* __restrict__ ia2, const int* __restrict__ ib2,
    const int* __restrict__ ia3, const int* __restrict__ ib3,
    const float4* __restrict__ c1, const float4* __restrict__ c2,
    const float4* __restrict__ c3,
    int* __restrict__ meta)        // [WIDTH][36]
{
    const int j = blockIdx.x * 256 + threadIdx.x;
    if (j >= WIDTH) return;

    const int pa = ia3[j], pb = ib3[j];
    const int qaa = ia2[pa], qab = ib2[pa];
    const int qba = ia2[pb], qbb = ib2[pb];

    int* M = meta + (size_t)j * MDW;
    M[0] = ia1[qaa]; M[1] = ib1[qaa];
    M[2] = ia1[qab]; M[3] = ib1[qab];
    M[4] = ia1[qba]; M[5] = ib1[qba];
    M[6] = ia1[qbb]; M[7] = ib1[qbb];

    float4* P = (float4*)(M + 8);
    P[0] = c1[qaa]; P[1] = c1[qab]; P[2] = c1[qba]; P[3] = c1[qbb];
    P[4] = c2[pa];  P[5] = c2[pb];
    P[6] = c3[j];
}

// ---------------------------------------------------------------- fused net
__global__ __launch_bounds__(1024, 4) void fused_kernel(
    const ushort_t* __restrict__ xT,
    const int*      __restrict__ meta,
    float*          __restrict__ red_out)
{
    __shared__ int    smeta[GPB3 * MDW];     // 36.9 KB block meta slice
    __shared__ float4 sred[NWAVE][64];       // 16 KB

    const int tid  = threadIdx.x;
    const int lane = tid & 63;
    const int wu   = __builtin_amdgcn_readfirstlane(tid >> 6);

    // ---- stage the block's meta slice ONCE (coalesced int4, ~2.25/thread)
    {
        const int4* src = (const int4*)(meta + (size_t)blockIdx.x * GPB3 * MDW);
        int4* dst = (int4*)smeta;
        for (int t = tid; t < MI4; t += 1024)
            dst[t] = src[t];
    }
    __syncthreads();

    float4 acc = make_float4(0.f, 0.f, 0.f, 0.f);

    #pragma unroll 2
    for (int i = 0; i < GPW3; ++i) {
        const int gl = wu * GPW3 + i;                 // block-local, uniform
        const int* mp = smeta + gl * MDW;             // LDS, broadcast reads

        const int4 iA = *(const int4*)(mp);           // ds_read_b128
        const int4 iB = *(const int4*)(mp + 4);
        const int c0 = __builtin_amdgcn_readfirstlane(iA.x);
        const int c1 = __builtin_amdgcn_readfirstlane(iA.y);
        const int c2 = __builtin_amdgcn_readfirstlane(iA.z);
        const int c3 = __builtin_amdgcn_readfirstlane(iA.w);
        const int c4 = __builtin_amdgcn_readfirstlane(iB.x);
        const int c5 = __builtin_amdgcn_readfirstlane(iB.y);
        const int c6 = __builtin_amdgcn_readfirstlane(iB.z);
        const int c7 = __builtin_amdgcn_readfirstlane(iB.w);

        // 8 saddr-form gathers from 0.5MB L2-resident xT; issue before coefs
        const uint2 q0 = ((const uint2*)(xT + (size_t)c0 * BATCH))[lane];
        const uint2 q1 = ((const uint2*)(xT + (size_t)c1 * BATCH))[lane];
        const uint2 q2 = ((const uint2*)(xT + (size_t)c2 * BATCH))[lane];
        const uint2 q3 = ((const uint2*)(xT + (size_t)c3 * BATCH))[lane];
        const uint2 q4 = ((const uint2*)(xT + (size_t)c4 * BATCH))[lane];
        const uint2 q5 = ((const uint2*)(xT + (size_t)c5 * BATCH))[lane];
        const uint2 q6 = ((const uint2*)(xT + (size_t)c6 * BATCH))[lane];
        const uint2 q7 = ((const uint2*)(xT + (size_t)c7 * BATCH))[lane];

        const float4 K0 = *(const float4*)(mp + 8);   // LDS b128, overlap
        const float4 K1 = *(const float4*)(mp + 12);  //   with gather latency
        const float4 K2 = *(const float4*)(mp + 16);
        const float4 K3 = *(const float4*)(mp + 20);
        const float4 K4 = *(const float4*)(mp + 24);
        const float4 K5 = *(const float4*)(mp + 28);
        const float4 K6 = *(const float4*)(mp + 32);

        const float4 haa = gate4u(K0, q0, q1);
        const float4 hab = gate4u(K1, q2, q3);
        const float4 hba = gate4u(K2, q4, q5);
        const float4 hbb = gate4u(K3, q6, q7);
        const float4 h2a = gate4(K4, haa, hab);
        const float4 h2b = gate4(K5, hba, hbb);
        const float4 h3  = gate4(K6, h2a, h2b);
        acc.x += h3.x; acc.y += h3.y; acc.z += h3.z; acc.w += h3.w;
    }

    // ---- block reduction + grouped atomic add (block fully inside a group)
    sred[wu][lane] = acc;
    __syncthreads();
    if (wu == 0) {
        float4 t = sred[0][lane];
        #pragma unroll
        for (int w = 1; w < NWAVE; ++w) {
            float4 q = sred[w][lane];
            t.x += q.x; t.y += q.y; t.z += q.z; t.w += q.w;
        }
        const float sc = 1.0f / TAU;
        const int grp = blockIdx.x / BPG;
        const int b0 = lane * 4;
        atomicAdd(&red_out[(b0 + 0) * NGROUP + grp], t.x * sc);
        atomicAdd(&red_out[(b0 + 1) * NGROUP + grp], t.y * sc);
        atomicAdd(&red_out[(b0 + 2) * NGROUP + grp], t.z * sc);
        atomicAdd(&red_out[(b0 + 3) * NGROUP + grp], t.w * sc);
    }
}

// ---------------------------------------------------------------- launch
extern "C" void kernel_launch(void* const* d_in, const int* in_sizes, int n_in,
                              void* d_out, int out_size, void* d_ws, size_t ws_size,
                              hipStream_t stream)
{
    const float* x   = (const float*)d_in[0];
    const float* w1  = (const float*)d_in[1];
    const float* w2  = (const float*)d_in[2];
    const float* w3  = (const float*)d_in[3];
    const int*   ia1 = (const int*)d_in[4];
    const int*   ib1 = (const int*)d_in[5];
    const int*   ia2 = (const int*)d_in[6];
    const int*   ib2 = (const int*)d_in[7];
    const int*   ia3 = (const int*)d_in[8];
    const int*   ib3 = (const int*)d_in[9];
    float* out = (float*)d_out;

    // workspace: xT (0.5MB) | meta (9.2MB) | c1,c2,c3 (3MB) ~= 12.7MB
    char* ws = (char*)d_ws;
    ushort_t* xT = (ushort_t*)ws;
    int*    meta = (int*)(ws + (size_t)IN_DIM * BATCH * 2);
    float4*   c1 = (float4*)(meta + (size_t)WIDTH * MDW);
    float4*   c2 = c1 + WIDTH;
    float4*   c3 = c2 + WIDTH;

    hipMemsetAsync(d_out, 0, (size_t)out_size * sizeof(float), stream);

    transpose_kernel<<<64, 256, 0, stream>>>(x, xT);
    coef_kernel<<<(3 * WIDTH) / 256, 256, 0, stream>>>(w1, w2, w3, c1, c2, c3);
    prep_kernel<<<WIDTH / 256, 256, 0, stream>>>(ia1, ib1, ia2, ib2, ia3, ib3,
                                                 c1, c2, c3, meta);
    fused_kernel<<<NBLK3, 1024, 0, stream>>>(xT, meta, out);
}

// Round 17
// 124.898 us; speedup vs baseline: 2.0318x; 1.0279x over previous
//
#include <hip/hip_runtime.h>
#include <stdint.h>

// DiffLogic: 3-layer differentiable logic network.
// Round 23: R22's container died twice with no counters -- the one unproven
// construct was the agent-scope atomic gather; de-risk by reverting to the
// byte-proven R19 fused kernel (127.3us artifact: SMEM meta via uniform
// index, gathers issued before coef s_loads, unroll 2, GPB 256, (1024,4)).
// Keep ONLY the safe half of R22: merged setup dispatch (memset+transpose+
// coef in one kernel, 5 -> 3 dispatches) to shave launch gaps.

#define BATCH   256
#define IN_DIM  1024
#define WIDTH   64000
#define NGROUP  10
#define GSIZE   6400      // WIDTH / NGROUP
#define TAU     30.0f
#define NWAVE   16        // waves per block (1024 threads)
#define GPB3    256       // gates per block; 6400 % 256 == 0 -> no straddle
#define GPW3    (GPB3/NWAVE)   // 16 gates per wave
#define NBLK3   (WIDTH/GPB3)   // 250 blocks -> 1 block/CU, single pass
#define BPG     (GSIZE/GPB3)   // 25 blocks per output group
#define MDW     36             // meta dwords per gate

#define TR_BLKS   64                   // transpose blocks
#define COEF_BLKS ((3*WIDTH)/256)      // 750
#define SETUP_BLKS (TR_BLKS + COEF_BLKS + 1)   // +1 zero-out block

typedef unsigned short ushort_t;

static __device__ __forceinline__ ushort_t f2bf(float f) {   // RNE
    uint32_t u = __float_as_uint(f);
    return (ushort_t)((u + 0x7fffu + ((u >> 16) & 1u)) >> 16);
}
static __device__ __forceinline__ float bfl(uint32_t u) {    // low bf16 -> f32
    return __uint_as_float(u << 16);
}
static __device__ __forceinline__ float bfh(uint32_t u) {    // high bf16 -> f32
    return __uint_as_float(u & 0xffff0000u);
}
// h = c0 + c1*a + c2*b + c3*(a*b) = b*(c3*a+c2) + (c1*a+c0)  -- 3 FMA
static __device__ __forceinline__ float gate1(float4 c, float a, float b) {
    return fmaf(b, fmaf(c.w, a, c.z), fmaf(c.y, a, c.x));
}
static __device__ __forceinline__ float4 gate4(float4 c, float4 a, float4 b) {
    float4 r;
    r.x = gate1(c, a.x, b.x);
    r.y = gate1(c, a.y, b.y);
    r.z = gate1(c, a.z, b.z);
    r.w = gate1(c, a.w, b.w);
    return r;
}
// packed inputs: a,b are uint2 holding 4 bf16 batch elems each
static __device__ __forceinline__ float4 gate4u(float4 c, uint2 a, uint2 b) {
    float4 r;
    r.x = gate1(c, bfl(a.x), bfl(b.x));
    r.y = gate1(c, bfh(a.x), bfh(b.x));
    r.z = gate1(c, bfl(a.y), bfl(b.y));
    r.w = gate1(c, bfh(a.y), bfh(b.y));
    return r;
}

// ---------------------------------------------------------------- setup
// One dispatch, three independent jobs by blockIdx:
//   [0, 64)        transpose x:(256,1024) f32 -> xT:(1024,256) bf16
//   [64, 64+750)   softmax coefficients for all 3 layers
//   [814]          zero the 10KB output accumulator
__global__ __launch_bounds__(256) void setup_kernel(
    const float* __restrict__ x,
    const float* __restrict__ w1, const float* __restrict__ w2,
    const float* __restrict__ w3,
    ushort_t* __restrict__ xT,
    float4* __restrict__ c1o, float4* __restrict__ c2o, float4* __restrict__ c3o,
    float* __restrict__ out_zero, int out_n)
{
    __shared__ float tile[64][65];
    const int bid = blockIdx.x;
    const int tid = threadIdx.x;

    if (bid < TR_BLKS) {
        const int c0 = (bid & 15) * 64;
        const int b0 = (bid >> 4) * 64;
        const int lt = tid & 63;
        const int wt = tid >> 6;
        for (int r = wt; r < 64; r += 4)
            tile[r][lt] = x[(b0 + r) * IN_DIM + c0 + lt];
        __syncthreads();
        for (int r = wt; r < 64; r += 4)
            xT[(c0 + r) * BATCH + b0 + lt] = f2bf(tile[lt][r]);
        return;
    }
    if (bid == TR_BLKS + COEF_BLKS) {
        for (int i = tid; i < out_n; i += 256) out_zero[i] = 0.f;
        return;
    }

    const int id = (bid - TR_BLKS) * 256 + tid;
    const int layer = id / WIDTH;
    const int j = id - layer * WIDTH;
    const float* w = (layer == 0) ? w1 : (layer == 1) ? w2 : w3;
    float4* cc     = (layer == 0) ? c1o : (layer == 1) ? c2o : c3o;

    const float4* w4 = (const float4*)(w + (size_t)j * 16);
    float4 q0 = w4[0], q1 = w4[1], q2 = w4[2], q3 = w4[3];
    float p[16] = {q0.x,q0.y,q0.z,q0.w, q1.x,q1.y,q1.z,q1.w,
                   q2.x,q2.y,q2.z,q2.w, q3.x,q3.y,q3.z,q3.w};
    float m = p[0];
    #pragma unroll
    for (int i = 1; i < 16; ++i) m = fmaxf(m, p[i]);
    float s = 0.f;
    #pragma unroll
    for (int i = 0; i < 16; ++i) { p[i] = __expf(p[i] - m); s += p[i]; }
    const float inv = 1.0f / s;
    float c0 = (p[8]+p[9]+p[10]+p[11]+p[12]+p[13]+p[14]+p[15]) * inv;
    float c1 = (p[2]+p[3]+p[6]+p[7] - p[8]-p[9]-p[12]-p[13]) * inv;
    float c2 = (p[4]+p[5]+p[6]+p[7] - p[8]-p[9]-p[10]-p[11]) * inv;
    float c3 = (p[1]-p[2]-p[4]-2.f*p[6]-p[7]+p[8]+2.f*p[9]+p[11]+p[13]-p[14]) * inv;
    cc[j] = make_float4(c0, c1, c2, c3);
}

// ---------------------------------------------------------------- tree prep
// One thread per final gate j: flatten its depth-3 tree into a single
// 36-dword record: [iA(4) | iB(4) | K0..K6(28)] -> s_loads in the hot loop.
__global__ __launch_bounds__(256) void prep_kernel(
    const int* __restrict__ ia1, const int* __restrict__ ib1,
    const int* __restrict__ ia2, const int* __restrict__ ib2,
    const int* __restrict__ ia3, const int* __restrict__ ib3,
    const float4* __restrict__ c1, const float4* __restrict__ c2,
    const float4* __restrict__ c3,
    int* __restrict__ meta)        // [WIDTH][36]
{
    const int j = blockIdx.x * 256 + threadIdx.x;
    if (j >= WIDTH) return;

    const int pa = ia3[j], pb = ib3[j];
    const int qaa = ia2[pa], qab = ib2[pa];
    const int qba = ia2[pb], qbb = ib2[pb];

    int* M = meta + (size_t)j * MDW;
    M[0] = ia1[qaa]; M[1] = ib1[qaa];
    M[2] = ia1[qab]; M[3] = ib1[qab];
    M[4] = ia1[qba]; M[5] = ib1[qba];
    M[6] = ia1[qbb]; M[7] = ib1[qbb];

    float4* P = (float4*)(M + 8);
    P[0] = c1[qaa]; P[1] = c1[qab]; P[2] = c1[qba]; P[3] = c1[qbb];
    P[4] = c2[pa];  P[5] = c2[pb];
    P[6] = c3[j];
}

// ---------------------------------------------------------------- fused net
__global__ __launch_bounds__(1024, 4) void fused_kernel(
    const ushort_t* __restrict__ xT,
    const int*      __restrict__ meta,
    float*          __restrict__ red_out)
{
    __shared__ float4 sred[NWAVE][64];       // 16 KB

    const int tid  = threadIdx.x;
    const int lane = tid & 63;
    const int wu   = __builtin_amdgcn_readfirstlane(tid >> 6);
    const int g0   = blockIdx.x * GPB3 + wu * GPW3;   // uniform

    float4 acc = make_float4(0.f, 0.f, 0.f, 0.f);

    #pragma unroll 2
    for (int i = 0; i < GPW3; ++i) {
        const int g = g0 + i;                         // uniform int index
        const int* mp = meta + (size_t)g * MDW;       // -> s_load
        const int4 iA   = *(const int4*)(mp);
        const int4 iB   = *(const int4*)(mp + 4);

        // issue the 8 gathers FIRST: their latency overlaps the coef drain
        const uint2 q0 = ((const uint2*)(xT + (size_t)iA.x * BATCH))[lane];
        const uint2 q1 = ((const uint2*)(xT + (size_t)iA.y * BATCH))[lane];
        const uint2 q2 = ((const uint2*)(xT + (size_t)iA.z * BATCH))[lane];
        const uint2 q3 = ((const uint2*)(xT + (size_t)iA.w * BATCH))[lane];
        const uint2 q4 = ((const uint2*)(xT + (size_t)iB.x * BATCH))[lane];
        const uint2 q5 = ((const uint2*)(xT + (size_t)iB.y * BATCH))[lane];
        const uint2 q6 = ((const uint2*)(xT + (size_t)iB.z * BATCH))[lane];
        const uint2 q7 = ((const uint2*)(xT + (size_t)iB.w * BATCH))[lane];

        const float4 K0 = *(const float4*)(mp + 8);   // s_load, behind gathers
        const float4 K1 = *(const float4*)(mp + 12);
        const float4 K2 = *(const float4*)(mp + 16);
        const float4 K3 = *(const float4*)(mp + 20);
        const float4 K4 = *(const float4*)(mp + 24);
        const float4 K5 = *(const float4*)(mp + 28);
        const float4 K6 = *(const float4*)(mp + 32);

        const float4 haa = gate4u(K0, q0, q1);
        const float4 hab = gate4u(K1, q2, q3);
        const float4 hba = gate4u(K2, q4, q5);
        const float4 hbb = gate4u(K3, q6, q7);
        const float4 h2a = gate4(K4, haa, hab);
        const float4 h2b = gate4(K5, hba, hbb);
        const float4 h3  = gate4(K6, h2a, h2b);
        acc.x += h3.x; acc.y += h3.y; acc.z += h3.z; acc.w += h3.w;
    }

    // ---- block reduction + grouped atomic add (block fully inside a group)
    sred[wu][lane] = acc;
    __syncthreads();
    if (wu == 0) {
        float4 t = sred[0][lane];
        #pragma unroll
        for (int w = 1; w < NWAVE; ++w) {
            float4 q = sred[w][lane];
            t.x += q.x; t.y += q.y; t.z += q.z; t.w += q.w;
        }
        const float sc = 1.0f / TAU;
        const int grp = blockIdx.x / BPG;
        const int b0 = lane * 4;
        atomicAdd(&red_out[(b0 + 0) * NGROUP + grp], t.x * sc);
        atomicAdd(&red_out[(b0 + 1) * NGROUP + grp], t.y * sc);
        atomicAdd(&red_out[(b0 + 2) * NGROUP + grp], t.z * sc);
        atomicAdd(&red_out[(b0 + 3) * NGROUP + grp], t.w * sc);
    }
}

// ---------------------------------------------------------------- launch
extern "C" void kernel_launch(void* const* d_in, const int* in_sizes, int n_in,
                              void* d_out, int out_size, void* d_ws, size_t ws_size,
                              hipStream_t stream)
{
    const float* x   = (const float*)d_in[0];
    const float* w1  = (const float*)d_in[1];
    const float* w2  = (const float*)d_in[2];
    const float* w3  = (const float*)d_in[3];
    const int*   ia1 = (const int*)d_in[4];
    const int*   ib1 = (const int*)d_in[5];
    const int*   ia2 = (const int*)d_in[6];
    const int*   ib2 = (const int*)d_in[7];
    const int*   ia3 = (const int*)d_in[8];
    const int*   ib3 = (const int*)d_in[9];
    float* out = (float*)d_out;

    // workspace: xT (0.5MB) | meta (9.2MB) | c1,c2,c3 (3MB) ~= 12.7MB
    char* ws = (char*)d_ws;
    ushort_t* xT = (ushort_t*)ws;
    int*    meta = (int*)(ws + (size_t)IN_DIM * BATCH * 2);
    float4*   c1 = (float4*)(meta + (size_t)WIDTH * MDW);
    float4*   c2 = c1 + WIDTH;
    float4*   c3 = c2 + WIDTH;

    setup_kernel<<<SETUP_BLKS, 256, 0, stream>>>(x, w1, w2, w3, xT,
                                                 c1, c2, c3, out, out_size);
    prep_kernel<<<WIDTH / 256, 256, 0, stream>>>(ia1, ib1, ia2, ib2, ia3, ib3,
                                                 c1, c2, c3, meta);
    fused_kernel<<<NBLK3, 1024, 0, stream>>>(xT, meta, out);
}

// Round 18
// 122.210 us; speedup vs baseline: 2.0765x; 1.0220x over previous
//
#include <hip/hip_runtime.h>
#include <stdint.h>

// DiffLogic: 3-layer differentiable logic network.
// Round 24: halve the line-fill count -- the proven fused wall (R22 model:
// 2000 wave-gathers/CU x 4 lines = ~28us; 6 structural variants pinned
// there). All LEAF values are raw x in [0,1) (flattened tree gathers only
// layer-0 inputs; intermediates stay fp32 in registers), so store leaves
// as u8 fixed-point round(x*255): column = 256B = 2 lines (was 4). The
// 1/255 scales fold into PREP-TIME layer-1 coefs (c1*s, c2*s, c3*s^2);
// hot-loop decode is (float)((q>>8k)&0xFF) -> v_cvt_f32_ubyteN, 1 op/elem
// (same as the bf16 shift it replaces). Quant error <= 0.002 = bf16-class.
// Everything else = the 124.9us R23 artifact (merged setup, SMEM meta,
// gathers-first, unroll 2, GPB 256, (1024,4)).

#define BATCH   256
#define IN_DIM  1024
#define WIDTH   64000
#define NGROUP  10
#define GSIZE   6400      // WIDTH / NGROUP
#define TAU     30.0f
#define NWAVE   16        // waves per block (1024 threads)
#define GPB3    256       // gates per block; 6400 % 256 == 0 -> no straddle
#define GPW3    (GPB3/NWAVE)   // 16 gates per wave
#define NBLK3   (WIDTH/GPB3)   // 250 blocks -> 1 block/CU, single pass
#define BPG     (GSIZE/GPB3)   // 25 blocks per output group
#define MDW     36             // meta dwords per gate

#define TR_BLKS   64                   // transpose blocks
#define COEF_BLKS ((3*WIDTH)/256)      // 750
#define SETUP_BLKS (TR_BLKS + COEF_BLKS + 1)   // +1 zero-out block

typedef unsigned short ushort_t;

// h = c0 + c1*a + c2*b + c3*(a*b) = b*(c3*a+c2) + (c1*a+c0)  -- 3 FMA
static __device__ __forceinline__ float gate1(float4 c, float a, float b) {
    return fmaf(b, fmaf(c.w, a, c.z), fmaf(c.y, a, c.x));
}
static __device__ __forceinline__ float4 gate4(float4 c, float4 a, float4 b) {
    float4 r;
    r.x = gate1(c, a.x, b.x);
    r.y = gate1(c, a.y, b.y);
    r.z = gate1(c, a.z, b.z);
    r.w = gate1(c, a.w, b.w);
    return r;
}
// u8-packed inputs: a,b are uint32 holding 4 fixed-point batch elems each.
// Coefs K carry the 1/255 scales (prep-time), so raw byte values feed FMA.
static __device__ __forceinline__ float ub(uint32_t u, int k) {
    return (float)((u >> (8 * k)) & 0xFFu);     // -> v_cvt_f32_ubyteN
}
static __device__ __forceinline__ float4 gate4b(float4 c, uint32_t a, uint32_t b) {
    float4 r;
    r.x = gate1(c, ub(a, 0), ub(b, 0));
    r.y = gate1(c, ub(a, 1), ub(b, 1));
    r.z = gate1(c, ub(a, 2), ub(b, 2));
    r.w = gate1(c, ub(a, 3), ub(b, 3));
    return r;
}

// ---------------------------------------------------------------- setup
// One dispatch, three independent jobs by blockIdx:
//   [0, 64)        transpose x:(256,1024) f32 -> xT8:(1024,256) u8 fixed
//   [64, 64+750)   softmax coefficients for all 3 layers
//   [814]          zero the 10KB output accumulator
__global__ __launch_bounds__(256) void setup_kernel(
    const float* __restrict__ x,
    const float* __restrict__ w1, const float* __restrict__ w2,
    const float* __restrict__ w3,
    uint8_t* __restrict__ xT8,
    float4* __restrict__ c1o, float4* __restrict__ c2o, float4* __restrict__ c3o,
    float* __restrict__ out_zero, int out_n)
{
    __shared__ float tile[64][65];
    const int bid = blockIdx.x;
    const int tid = threadIdx.x;

    if (bid < TR_BLKS) {
        const int c0 = (bid & 15) * 64;
        const int b0 = (bid >> 4) * 64;
        const int lt = tid & 63;
        const int wt = tid >> 6;
        for (int r = wt; r < 64; r += 4)
            tile[r][lt] = x[(b0 + r) * IN_DIM + c0 + lt];
        __syncthreads();
        for (int r = wt; r < 64; r += 4) {
            const float v = tile[lt][r];
            xT8[(c0 + r) * BATCH + b0 + lt] =
                (uint8_t)__float2int_rn(v * 255.0f);
        }
        return;
    }
    if (bid == TR_BLKS + COEF_BLKS) {
        for (int i = tid; i < out_n; i += 256) out_zero[i] = 0.f;
        return;
    }

    const int id = (bid - TR_BLKS) * 256 + tid;
    const int layer = id / WIDTH;
    const int j = id - layer * WIDTH;
    const float* w = (layer == 0) ? w1 : (layer == 1) ? w2 : w3;
    float4* cc     = (layer == 0) ? c1o : (layer == 1) ? c2o : c3o;

    const float4* w4 = (const float4*)(w + (size_t)j * 16);
    float4 q0 = w4[0], q1 = w4[1], q2 = w4[2], q3 = w4[3];
    float p[16] = {q0.x,q0.y,q0.z,q0.w, q1.x,q1.y,q1.z,q1.w,
                   q2.x,q2.y,q2.z,q2.w, q3.x,q3.y,q3.z,q3.w};
    float m = p[0];
    #pragma unroll
    for (int i = 1; i < 16; ++i) m = fmaxf(m, p[i]);
    float s = 0.f;
    #pragma unroll
    for (int i = 0; i < 16; ++i) { p[i] = __expf(p[i] - m); s += p[i]; }
    const float inv = 1.0f / s;
    float c0 = (p[8]+p[9]+p[10]+p[11]+p[12]+p[13]+p[14]+p[15]) * inv;
    float c1 = (p[2]+p[3]+p[6]+p[7] - p[8]-p[9]-p[12]-p[13]) * inv;
    float c2 = (p[4]+p[5]+p[6]+p[7] - p[8]-p[9]-p[10]-p[11]) * inv;
    float c3 = (p[1]-p[2]-p[4]-2.f*p[6]-p[7]+p[8]+2.f*p[9]+p[11]+p[13]-p[14]) * inv;
    cc[j] = make_float4(c0, c1, c2, c3);
}

// ---------------------------------------------------------------- tree prep
// One thread per final gate j: flatten its depth-3 tree into a single
// 36-dword record [iA(4)|iB(4)|K0..K6(28)]. Layer-1 coefs K0..K3 absorb the
// u8 fixed-point scale s=1/255: (c0, c1*s, c2*s, c3*s^2). K4..K6 unscaled.
__global__ __launch_bounds__(256) void prep_kernel(
    const int* __restrict__ ia1, const int* __restrict__ ib1,
    const int* __restrict__ ia2, const int* __restrict__ ib2,
    const int* __restrict__ ia3, const int* __restrict__ ib3,
    const float4* __restrict__ c1, const float4* __restrict__ c2,
    const float4* __restrict__ c3,
    int* __restrict__ meta)        // [WIDTH][36]
{
    const int j = blockIdx.x * 256 + threadIdx.x;
    if (j >= WIDTH) return;

    const int pa = ia3[j], pb = ib3[j];
    const int qaa = ia2[pa], qab = ib2[pa];
    const int qba = ia2[pb], qbb = ib2[pb];

    int* M = meta + (size_t)j * MDW;
    M[0] = ia1[qaa]; M[1] = ib1[qaa];
    M[2] = ia1[qab]; M[3] = ib1[qab];
    M[4] = ia1[qba]; M[5] = ib1[qba];
    M[6] = ia1[qbb]; M[7] = ib1[qbb];

    const float s1 = 1.0f / 255.0f;
    const float s2 = s1 * s1;
    float4* P = (float4*)(M + 8);
    float4 k;
    k = c1[qaa]; P[0] = make_float4(k.x, k.y * s1, k.z * s1, k.w * s2);
    k = c1[qab]; P[1] = make_float4(k.x, k.y * s1, k.z * s1, k.w * s2);
    k = c1[qba]; P[2] = make_float4(k.x, k.y * s1, k.z * s1, k.w * s2);
    k = c1[qbb]; P[3] = make_float4(k.x, k.y * s1, k.z * s1, k.w * s2);
    P[4] = c2[pa];  P[5] = c2[pb];
    P[6] = c3[j];
}

// ---------------------------------------------------------------- fused net
__global__ __launch_bounds__(1024, 4) void fused_kernel(
    const uint8_t* __restrict__ xT8,
    const int*     __restrict__ meta,
    float*         __restrict__ red_out)
{
    __shared__ float4 sred[NWAVE][64];       // 16 KB

    const int tid  = threadIdx.x;
    const int lane = tid & 63;
    const int wu   = __builtin_amdgcn_readfirstlane(tid >> 6);
    const int g0   = blockIdx.x * GPB3 + wu * GPW3;   // uniform

    float4 acc = make_float4(0.f, 0.f, 0.f, 0.f);

    #pragma unroll 2
    for (int i = 0; i < GPW3; ++i) {
        const int g = g0 + i;                         // uniform int index
        const int* mp = meta + (size_t)g * MDW;       // -> s_load
        const int4 iA   = *(const int4*)(mp);
        const int4 iB   = *(const int4*)(mp + 4);

        // 8 gathers, 256B/column = 2 cache lines (was 4); issue before coefs
        const uint32_t q0 = ((const uint32_t*)(xT8 + (size_t)iA.x * BATCH))[lane];
        const uint32_t q1 = ((const uint32_t*)(xT8 + (size_t)iA.y * BATCH))[lane];
        const uint32_t q2 = ((const uint32_t*)(xT8 + (size_t)iA.z * BATCH))[lane];
        const uint32_t q3 = ((const uint32_t*)(xT8 + (size_t)iA.w * BATCH))[lane];
        const uint32_t q4 = ((const uint32_t*)(xT8 + (size_t)iB.x * BATCH))[lane];
        const uint32_t q5 = ((const uint32_t*)(xT8 + (size_t)iB.y * BATCH))[lane];
        const uint32_t q6 = ((const uint32_t*)(xT8 + (size_t)iB.z * BATCH))[lane];
        const uint32_t q7 = ((const uint32_t*)(xT8 + (size_t)iB.w * BATCH))[lane];

        const float4 K0 = *(const float4*)(mp + 8);   // s_load, behind gathers
        const float4 K1 = *(const float4*)(mp + 12);
        const float4 K2 = *(const float4*)(mp + 16);
        const float4 K3 = *(const float4*)(mp + 20);
        const float4 K4 = *(const float4*)(mp + 24);
        const float4 K5 = *(const float4*)(mp + 28);
        const float4 K6 = *(const float4*)(mp + 32);

        const float4 haa = gate4b(K0, q0, q1);
        const float4 hab = gate4b(K1, q2, q3);
        const float4 hba = gate4b(K2, q4, q5);
        const float4 hbb = gate4b(K3, q6, q7);
        const float4 h2a = gate4(K4, haa, hab);
        const float4 h2b = gate4(K5, hba, hbb);
        const float4 h3  = gate4(K6, h2a, h2b);
        acc.x += h3.x; acc.y += h3.y; acc.z += h3.z; acc.w += h3.w;
    }

    // ---- block reduction + grouped atomic add (block fully inside a group)
    sred[wu][lane] = acc;
    __syncthreads();
    if (wu == 0) {
        float4 t = sred[0][lane];
        #pragma unroll
        for (int w = 1; w < NWAVE; ++w) {
            float4 q = sred[w][lane];
            t.x += q.x; t.y += q.y; t.z += q.z; t.w += q.w;
        }
        const float sc = 1.0f / TAU;
        const int grp = blockIdx.x / BPG;
        const int b0 = lane * 4;
        atomicAdd(&red_out[(b0 + 0) * NGROUP + grp], t.x * sc);
        atomicAdd(&red_out[(b0 + 1) * NGROUP + grp], t.y * sc);
        atomicAdd(&red_out[(b0 + 2) * NGROUP + grp], t.z * sc);
        atomicAdd(&red_out[(b0 + 3) * NGROUP + grp], t.w * sc);
    }
}

// ---------------------------------------------------------------- launch
extern "C" void kernel_launch(void* const* d_in, const int* in_sizes, int n_in,
                              void* d_out, int out_size, void* d_ws, size_t ws_size,
                              hipStream_t stream)
{
    const float* x   = (const float*)d_in[0];
    const float* w1  = (const float*)d_in[1];
    const float* w2  = (const float*)d_in[2];
    const float* w3  = (const float*)d_in[3];
    const int*   ia1 = (const int*)d_in[4];
    const int*   ib1 = (const int*)d_in[5];
    const int*   ia2 = (const int*)d_in[6];
    const int*   ib2 = (const int*)d_in[7];
    const int*   ia3 = (const int*)d_in[8];
    const int*   ib3 = (const int*)d_in[9];
    float* out = (float*)d_out;

    // workspace: xT8 (0.25MB) | meta (9.2MB) | c1,c2,c3 (3MB) ~= 12.5MB
    char* ws = (char*)d_ws;
    uint8_t* xT8 = (uint8_t*)ws;
    int*    meta = (int*)(ws + (size_t)IN_DIM * BATCH);
    float4*   c1 = (float4*)(meta + (size_t)WIDTH * MDW);
    float4*   c2 = c1 + WIDTH;
    float4*   c3 = c2 + WIDTH;

    setup_kernel<<<SETUP_BLKS, 256, 0, stream>>>(x, w1, w2, w3, xT8,
                                                 c1, c2, c3, out, out_size);
    prep_kernel<<<WIDTH / 256, 256, 0, stream>>>(ia1, ib1, ia2, ib2, ia3, ib3,
                                                 c1, c2, c3, meta);
    fused_kernel<<<NBLK3, 1024, 0, stream>>>(xT8, meta, out);
}